// Round 8
// baseline (172.949 us; speedup 1.0000x reference)
//
#include <hip/hip_runtime.h>

#define IMG 224
#define HW (IMG * IMG)
#define TILE 32
#define PAD 4
#define REG (TILE + 2 * PAD)   // 40: staged rows/cols per tile
#define RSA 41                 // A-table row stride in float2 units (odd)
#define TABA (REG * RSA)       // 1640 float2 per image (ch0,ch1 packed)
#define RSB 44                 // B-table row stride in floats (mult of 4)
#define TABB (REG * RSB)       // 1760 floats per image (ch2)

#define NXCD 8
#define NWG  (49 * 64)         // 3136 logical tiles
#define NBLK (NWG / 2)         // 1568 hw blocks, 2 tiles each; 1568 % 8 == 0

// native clang vector for __builtin_nontemporal_* (HIP_vector_type rejected)
typedef float vfloat4 __attribute__((ext_vector_type(4)));

struct Unit { float4 a, b, c; };   // 4 px of ch0/ch1/ch2

__device__ __forceinline__ Unit load_unit(const float* __restrict__ src, int gi) {
    Unit u;
    if (gi >= 0 && gi <= HW - 4) {
        u.a = *(const float4*)(src + gi);
        u.b = *(const float4*)(src + HW + gi);
        u.c = *(const float4*)(src + 2 * HW + gi);
    } else {                        // flat-clamp edge rows (rare tiles)
#pragma unroll
        for (int i = 0; i < 4; ++i) {
            int g = min(max(gi + i, 0), HW - 1);
            ((float*)&u.a)[i] = src[g];
            ((float*)&u.b)[i] = src[HW + g];
            ((float*)&u.c)[i] = src[2 * HW + g];
        }
    }
    return u;
}

__device__ __forceinline__ void write_unit(float2* TA, float* TB,
                                           int r, int s, const Unit& u) {
    float2* dA = TA + r * RSA + 4 * s;
    dA[0] = make_float2(u.a.x, u.b.x);
    dA[1] = make_float2(u.a.y, u.b.y);
    dA[2] = make_float2(u.a.z, u.b.z);
    dA[3] = make_float2(u.a.w, u.b.w);
    *(float4*)(TB + r * RSB + 4 * s) = u.c;     // (r*44+4s) % 4 == 0
}

__device__ __forceinline__ void compute_tile(
    int x0, int y0, int xlo, int ylo, int tx, int ty0, int p,
    const float2* __restrict__ tabA, const float* __restrict__ tabB,
    vfloat4 c0v, vfloat4 c1v, vfloat4 m1v, vfloat4 m2v,
    const float* __restrict__ i1n, const float* __restrict__ i2n,
    float* __restrict__ on)
{
    const float xf = (float)(x0 + tx);
    float acc0[4], acc1[4], acc2[4];

#pragma unroll
    for (int i = 0; i < 4; ++i) {
        const float yf  = (float)(y0 + ty0 + i);
        const float cc0 = c0v[i];
        const float cc1 = c1v[i];
        const float m1i = m1v[i];
        const float m2i = m2v[i];
        float r0c, r1c, r2c;

        {   // +C on im1
            float px = xf + cc0, py = yf + cc1;
            float fx = floorf(px), cx = ceilf(px);
            float fy = floorf(py), cy = ceilf(py);
            float wfx = 1.0f - (px - fx), wcx = 1.0f - (cx - px);
            float wfy = 1.0f - (py - fy), wcy = 1.0f - (cy - py);
            float w0 = wfx * wfy, w1 = wcx * wfy;
            float w2 = wfx * wcy, w3 = wcx * wcy;
            int gx0 = (int)fx, gy0 = (int)fy;
            int dx = (int)cx - gx0, dy = (int)cy - gy0;
            int q0 = gx0 - xlo, r0 = gy0 - ylo;
            int in = (q0 >= 0) & (q0 + dx <= REG - 1) &
                     (r0 >= 0) & (r0 + dy <= REG - 1);
            if (__all(in)) {
                int oA = r0 * RSA + q0;
                int oB = r0 * RSB + q0;
                float2 a0 = tabA[oA],            a1 = tabA[oA + dx];
                float2 a2 = tabA[oA + dy * RSA], a3 = tabA[oA + dx + dy * RSA];
                float  b0 = tabB[oB],            b1 = tabB[oB + dx];
                float  b2 = tabB[oB + dy * RSB], b3 = tabB[oB + dx + dy * RSB];
                r0c = m1i * (w0 * a0.x + w1 * a1.x + w2 * a2.x + w3 * a3.x);
                r1c = m1i * (w0 * a0.y + w1 * a1.y + w2 * a2.y + w3 * a3.y);
                r2c = m1i * (w0 * b0   + w1 * b1   + w2 * b2   + w3 * b3);
            } else {   // rare: displacement beyond PAD -> global clamped gather
                int i0 = min(max(gx0      + IMG * gy0,        0), HW - 1);
                int i1 = min(max(gx0 + dx + IMG * gy0,        0), HW - 1);
                int i2 = min(max(gx0      + IMG * (gy0 + dy), 0), HW - 1);
                int i3 = min(max(gx0 + dx + IMG * (gy0 + dy), 0), HW - 1);
                r0c = m1i * (w0 * i1n[i0] + w1 * i1n[i1] +
                             w2 * i1n[i2] + w3 * i1n[i3]);
                r1c = m1i * (w0 * i1n[HW + i0] + w1 * i1n[HW + i1] +
                             w2 * i1n[HW + i2] + w3 * i1n[HW + i3]);
                r2c = m1i * (w0 * i1n[2 * HW + i0] + w1 * i1n[2 * HW + i1] +
                             w2 * i1n[2 * HW + i2] + w3 * i1n[2 * HW + i3]);
            }
        }
        {   // -C on im2
            float px = xf - cc0, py = yf - cc1;
            float fx = floorf(px), cx = ceilf(px);
            float fy = floorf(py), cy = ceilf(py);
            float wfx = 1.0f - (px - fx), wcx = 1.0f - (cx - px);
            float wfy = 1.0f - (py - fy), wcy = 1.0f - (cy - py);
            float w0 = wfx * wfy, w1 = wcx * wfy;
            float w2 = wfx * wcy, w3 = wcx * wcy;
            int gx0 = (int)fx, gy0 = (int)fy;
            int dx = (int)cx - gx0, dy = (int)cy - gy0;
            int q0 = gx0 - xlo, r0 = gy0 - ylo;
            int in = (q0 >= 0) & (q0 + dx <= REG - 1) &
                     (r0 >= 0) & (r0 + dy <= REG - 1);
            if (__all(in)) {
                const float2* TA = tabA + TABA;
                const float*  TB = tabB + TABB;
                int oA = r0 * RSA + q0;
                int oB = r0 * RSB + q0;
                float2 a0 = TA[oA],            a1 = TA[oA + dx];
                float2 a2 = TA[oA + dy * RSA], a3 = TA[oA + dx + dy * RSA];
                float  b0 = TB[oB],            b1 = TB[oB + dx];
                float  b2 = TB[oB + dy * RSB], b3 = TB[oB + dx + dy * RSB];
                r0c += m2i * (w0 * a0.x + w1 * a1.x + w2 * a2.x + w3 * a3.x);
                r1c += m2i * (w0 * a0.y + w1 * a1.y + w2 * a2.y + w3 * a3.y);
                r2c += m2i * (w0 * b0   + w1 * b1   + w2 * b2   + w3 * b3);
            } else {
                int i0 = min(max(gx0      + IMG * gy0,        0), HW - 1);
                int i1 = min(max(gx0 + dx + IMG * gy0,        0), HW - 1);
                int i2 = min(max(gx0      + IMG * (gy0 + dy), 0), HW - 1);
                int i3 = min(max(gx0 + dx + IMG * (gy0 + dy), 0), HW - 1);
                r0c += m2i * (w0 * i2n[i0] + w1 * i2n[i1] +
                              w2 * i2n[i2] + w3 * i2n[i3]);
                r1c += m2i * (w0 * i2n[HW + i0] + w1 * i2n[HW + i1] +
                              w2 * i2n[HW + i2] + w3 * i2n[HW + i3]);
                r2c += m2i * (w0 * i2n[2 * HW + i0] + w1 * i2n[2 * HW + i1] +
                              w2 * i2n[2 * HW + i2] + w3 * i2n[2 * HW + i3]);
            }
        }
        acc0[i] = r0c; acc1[i] = r1c; acc2[i] = r2c;
    }

    vfloat4 s0 = {acc0[0], acc0[1], acc0[2], acc0[3]};
    vfloat4 s1 = {acc1[0], acc1[1], acc1[2], acc1[3]};
    vfloat4 s2 = {acc2[0], acc2[1], acc2[2], acc2[3]};
    __builtin_nontemporal_store(s0, (vfloat4*)(on + p));
    __builtin_nontemporal_store(s1, (vfloat4*)(on + HW + p));
    __builtin_nontemporal_store(s2, (vfloat4*)(on + 2 * HW + p));
}

__global__ __launch_bounds__(256, 3) void vm_kernel(
    const float* __restrict__ im1, const float* __restrict__ im2,
    const float* __restrict__ C, const float* __restrict__ M1,
    const float* __restrict__ M2, float* __restrict__ out)
{
    __shared__ float2 tabA[2 * TABA];
    __shared__ float  tabB[2 * TABB];

    // XCD-aware swizzle (bijective; 1568 % 8 == 0): each XCD owns a
    // contiguous run of tile-pairs = 8 whole batch images -> halo re-reads
    // stay in that XCD's L2 (verified: FETCH 150 -> 63 MB in R7).
    const int bid = blockIdx.x;
    const int swz = (bid & (NXCD - 1)) * (NBLK / NXCD) + (bid >> 3);
    const int l0  = swz * 2;               // this block's two logical tiles

    const int t    = threadIdx.x;
    const int tx   = t >> 3;               // 0..31 (slow coord, p / 224)
    const int ty0  = (t & 7) * 4;          // 0,4,..,28 (fast coord base)
    const bool has1 = (t < 144);           // owns a second staging unit
    const int r0u = t / 10,         s0u = t - r0u * 10;          // unit e=t
    const int r1u = (t + 256) / 10, s1u = (t + 256) - r1u * 10;  // e=t+256

    // =================== tile 0: geometry + issue loads ===================
    const int n0  = l0 / 49, tl0 = l0 - n0 * 49;
    const int x00 = (tl0 / 7) * TILE, y00 = (tl0 % 7) * TILE;
    const int xlo0 = x00 - PAD, ylo0 = y00 - PAD;
    const int gb0  = xlo0 + IMG * ylo0;
    const float* i1n0 = im1 + (size_t)n0 * 3 * HW;
    const float* i2n0 = im2 + (size_t)n0 * 3 * HW;
    const float* Cn0  = C   + (size_t)n0 * 2 * HW;
    const int p0 = (x00 + tx) * IMG + (y00 + ty0);

    Unit u1a = load_unit(i1n0, gb0 + IMG * r0u + 4 * s0u);
    Unit u2a = load_unit(i2n0, gb0 + IMG * r0u + 4 * s0u);
    Unit u1b, u2b;
    if (has1) {
        u1b = load_unit(i1n0, gb0 + IMG * r1u + 4 * s1u);
        u2b = load_unit(i2n0, gb0 + IMG * r1u + 4 * s1u);
    }
    const vfloat4 c0v0 = __builtin_nontemporal_load((const vfloat4*)(Cn0 + p0));
    const vfloat4 c1v0 = __builtin_nontemporal_load((const vfloat4*)(Cn0 + HW + p0));
    const vfloat4 m1v0 = __builtin_nontemporal_load(
        (const vfloat4*)(M1 + (size_t)n0 * HW + p0));
    const vfloat4 m2v0 = __builtin_nontemporal_load(
        (const vfloat4*)(M2 + (size_t)n0 * HW + p0));

    // write tile0 into LDS (compiler inserts the vmcnt waits)
    write_unit(tabA, tabB, r0u, s0u, u1a);
    write_unit(tabA + TABA, tabB + TABB, r0u, s0u, u2a);
    if (has1) {
        write_unit(tabA, tabB, r1u, s1u, u1b);
        write_unit(tabA + TABA, tabB + TABB, r1u, s1u, u2b);
    }
    __syncthreads();

    // ============ tile 1: issue loads BEFORE computing tile 0 =============
    const int l1  = l0 + 1;
    const int n1  = l1 / 49, tl1 = l1 - n1 * 49;
    const int x01 = (tl1 / 7) * TILE, y01 = (tl1 % 7) * TILE;
    const int xlo1 = x01 - PAD, ylo1 = y01 - PAD;
    const int gb1  = xlo1 + IMG * ylo1;
    const float* i1n1 = im1 + (size_t)n1 * 3 * HW;
    const float* i2n1 = im2 + (size_t)n1 * 3 * HW;
    const float* Cn1  = C   + (size_t)n1 * 2 * HW;
    const int p1 = (x01 + tx) * IMG + (y01 + ty0);

    Unit v1a = load_unit(i1n1, gb1 + IMG * r0u + 4 * s0u);
    Unit v2a = load_unit(i2n1, gb1 + IMG * r0u + 4 * s0u);
    Unit v1b, v2b;
    if (has1) {
        v1b = load_unit(i1n1, gb1 + IMG * r1u + 4 * s1u);
        v2b = load_unit(i2n1, gb1 + IMG * r1u + 4 * s1u);
    }
    const vfloat4 c0v1 = __builtin_nontemporal_load((const vfloat4*)(Cn1 + p1));
    const vfloat4 c1v1 = __builtin_nontemporal_load((const vfloat4*)(Cn1 + HW + p1));
    const vfloat4 m1v1 = __builtin_nontemporal_load(
        (const vfloat4*)(M1 + (size_t)n1 * HW + p1));
    const vfloat4 m2v1 = __builtin_nontemporal_load(
        (const vfloat4*)(M2 + (size_t)n1 * HW + p1));

    // ---- compute tile 0 (tile1 loads in flight underneath)
    compute_tile(x00, y00, xlo0, ylo0, tx, ty0, p0, tabA, tabB,
                 c0v0, c1v0, m1v0, m2v0, i1n0, i2n0,
                 out + (size_t)n0 * 3 * HW);

    __syncthreads();                       // all waves done reading tile0 LDS

    // ---- write tile 1 into LDS (loads should have landed by now)
    write_unit(tabA, tabB, r0u, s0u, v1a);
    write_unit(tabA + TABA, tabB + TABB, r0u, s0u, v2a);
    if (has1) {
        write_unit(tabA, tabB, r1u, s1u, v1b);
        write_unit(tabA + TABA, tabB + TABB, r1u, s1u, v2b);
    }
    __syncthreads();

    // ---- compute tile 1
    compute_tile(x01, y01, xlo1, ylo1, tx, ty0, p1, tabA, tabB,
                 c0v1, c1v1, m1v1, m2v1, i1n1, i2n1,
                 out + (size_t)n1 * 3 * HW);
}

extern "C" void kernel_launch(void* const* d_in, const int* in_sizes, int n_in,
                              void* d_out, int out_size, void* d_ws, size_t ws_size,
                              hipStream_t stream) {
    const float* im1 = (const float*)d_in[0];
    const float* im2 = (const float*)d_in[1];
    const float* C   = (const float*)d_in[2];
    const float* M1  = (const float*)d_in[3];
    const float* M2  = (const float*)d_in[4];
    float* out = (float*)d_out;
    vm_kernel<<<dim3(NBLK), 256, 0, stream>>>(im1, im2, C, M1, M2, out);
}